// Round 1
// baseline (121.867 us; speedup 1.0000x reference)
//
#include <hip/hip_runtime.h>
#include <stdint.h>

#define N 4096
#define D 1024            // elements per row; fp8 => 1024 bytes per row
#define MARGIN 0.1f
#define BM 256            // R10: block rows (was 128)
#define BN 128            // block cols
#define BKB 128           // K-slab per tile in fp8 bytes (=128 elements)

typedef __attribute__((ext_vector_type(4))) float f32x4;

// Kernel 1: one wave per row (4 rows/block): fp32 norms + diagonal dot,
// butterfly shfl_xor reduce, write normalized rows as OCP fp8 e4m3
// (v_cvt_pk_fp8_f32, 4 values packed per int). Block 0 zeroes d_out.
// d_i is kept in fp32 — the only N-correlated error path stays exact.
__global__ __launch_bounds__(256) void prep_kernel(
    const float* __restrict__ W, const float* __restrict__ O,
    uint8_t* __restrict__ Wn, uint8_t* __restrict__ On,
    float* __restrict__ dvec, float* __restrict__ out) {
  const int wv = threadIdx.x >> 6, ln = threadIdx.x & 63;
  const int row = blockIdx.x * 4 + wv;
  if (blockIdx.x == 0 && threadIdx.x == 0) *out = 0.0f;
  const float4* Wr = (const float4*)(W + (size_t)row * D);
  const float4* Or = (const float4*)(O + (size_t)row * D);
  float4 w[4], o[4];
  float sw = 0.f, so = 0.f, sd = 0.f;
  #pragma unroll
  for (int c = 0; c < 4; ++c) {
    w[c] = Wr[ln + c * 64];
    o[c] = Or[ln + c * 64];
    sw += w[c].x * w[c].x + w[c].y * w[c].y + w[c].z * w[c].z + w[c].w * w[c].w;
    so += o[c].x * o[c].x + o[c].y * o[c].y + o[c].z * o[c].z + o[c].w * o[c].w;
    sd += w[c].x * o[c].x + w[c].y * o[c].y + w[c].z * o[c].z + w[c].w * o[c].w;
  }
  #pragma unroll
  for (int off = 1; off < 64; off <<= 1) {
    sw += __shfl_xor(sw, off, 64);
    so += __shfl_xor(so, off, 64);
    sd += __shfl_xor(sd, off, 64);
  }
  const float inw = 1.0f / sqrtf(sw);
  const float ino = 1.0f / sqrtf(so);
  if (ln == 0) dvec[row] = sd * inw * ino;
  int* Wo = (int*)(Wn + (size_t)row * D);
  int* Oo = (int*)(On + (size_t)row * D);
  #pragma unroll
  for (int c = 0; c < 4; ++c) {
    int pw = __builtin_amdgcn_cvt_pk_fp8_f32(w[c].x * inw, w[c].y * inw, 0, false);
    pw = __builtin_amdgcn_cvt_pk_fp8_f32(w[c].z * inw, w[c].w * inw, pw, true);
    int po = __builtin_amdgcn_cvt_pk_fp8_f32(o[c].x * ino, o[c].y * ino, 0, false);
    po = __builtin_amdgcn_cvt_pk_fp8_f32(o[c].z * ino, o[c].w * ino, po, true);
    Wo[ln + c * 64] = pw;
    Oo[ln + c * 64] = po;
  }
}

// Kernel 2: 256x128-tile FP8 MFMA GEMM + fused contrastive-loss epilogue.
// R10 thesis: R9 is LDS-READ-pipe-bound. At 64x64 wave tiles, per block
// per kt: 64 KB frag reads (~900 cyc @73 B/cyc) vs ~310 cyc MFMA (3:1).
// Fix = raise arithmetic intensity per wave: 128x64 wave tile = 85 FLOP
// per LDS byte (vs 64). Block 256x128, same 4 waves => frag bytes/FLOP
// -25%, staging bytes/FLOP and barriers/FLOP -50%. acc 8x4 f32x4 = 128
// VGPR (~200 total, 2 waves/SIMD); LDS 48 KB; grid 512 = 2 blocks/CU for
// cross-block barrier-drain overlap (m114). Single-buffered (dbuf at this
// structure proven neutral m99/m100, and would force 1 block/CU here).
// Swizzle unchanged: 16B granule g of row r stored at slot g^(r&7) ->
// ds_read_b64 lands 2 lanes/bank (free, m136).
__global__ __launch_bounds__(256) void gemm_loss_kernel(
    const uint8_t* __restrict__ Wn, const uint8_t* __restrict__ On,
    const float* __restrict__ dvec, float* __restrict__ out) {
  __shared__ __align__(16) uint8_t ldsA[BM * BKB];  // 32 KB
  __shared__ __align__(16) uint8_t ldsB[BN * BKB];  // 16 KB
  const int bx = blockIdx.x, by = blockIdx.y;
  const int t = threadIdx.x;
  const int wv = t >> 6, ln = t & 63;
  const int wm = wv >> 1, wn = wv & 1;   // 2x2 wave grid, 128x64 per wave
  const int lrow = ln & 15;
  const int quad = ln >> 4;
  const int l7 = lrow & 7;               // == rr&7 == cc&7 for fragment rows
  const int sub = (quad & 1) * 8;        // low/high half of a 16B granule

  f32x4 acc[8][4] = {};

  const uint8_t* Ag = Wn + (size_t)(by * BM) * D;
  const uint8_t* Bg = On + (size_t)(bx * BN) * D;

  for (int kt = 0; kt < D / BKB; ++kt) {           // 8 iterations
    // stage A: 256 rows x 128 B = 2048 granules(16B); 256 thr x 8 rounds
    #pragma unroll
    for (int c = 0; c < 8; ++c) {
      const int g = c * 256 + t;         // granule index (fixed LDS slot)
      const int r = g >> 3;              // tile row (8 granules per row)
      const int gi = g & 7;              // granule slot within row
      const int col = (gi ^ (r & 7)) << 4;  // swizzled global byte col
      __builtin_amdgcn_global_load_lds(
          (const __attribute__((address_space(1))) void*)(Ag + (size_t)r * D + kt * BKB + col),
          (__attribute__((address_space(3))) void*)(ldsA + g * 16), 16, 0, 0);
    }
    // stage B: 128 rows x 128 B = 1024 granules; 256 thr x 4 rounds
    #pragma unroll
    for (int c = 0; c < 4; ++c) {
      const int g = c * 256 + t;
      const int r = g >> 3;
      const int gi = g & 7;
      const int col = (gi ^ (r & 7)) << 4;
      __builtin_amdgcn_global_load_lds(
          (const __attribute__((address_space(1))) void*)(Bg + (size_t)r * D + kt * BKB + col),
          (__attribute__((address_space(3))) void*)(ldsB + g * 16), 16, 0, 0);
    }
    __syncthreads();
    #pragma unroll
    for (int kk = 0; kk < 4; ++kk) {     // k = kk*32 within the slab
      const int gh = kk * 2 + (quad >> 1);  // 16B granule holding this octet
      long aF[8], bF[4];
      #pragma unroll
      for (int mi = 0; mi < 8; ++mi) {
        const int rr = wm * 128 + mi * 16 + lrow;
        aF[mi] = *(const long*)(ldsA + rr * BKB + ((gh ^ l7) << 4) + sub);
      }
      #pragma unroll
      for (int ni = 0; ni < 4; ++ni) {
        const int cc = wn * 64 + ni * 16 + lrow;
        bF[ni] = *(const long*)(ldsB + cc * BKB + ((gh ^ l7) << 4) + sub);
      }
      #pragma unroll
      for (int mi = 0; mi < 8; ++mi)
        #pragma unroll
        for (int ni = 0; ni < 4; ++ni)
          acc[mi][ni] = __builtin_amdgcn_mfma_f32_16x16x32_fp8_fp8(
              aF[mi], bF[ni], acc[mi][ni], 0, 0, 0);
    }
    __syncthreads();
  }

  // Epilogue: C/D layout col=lane&15, row=quad*4+reg (dtype-independent,
  // verified m89/m121; confirmed in-session by R2 absmax=0)
  float lsum = 0.0f;
  #pragma unroll
  for (int mi = 0; mi < 8; ++mi) {
    const int gibase = by * BM + wm * 128 + mi * 16 + quad * 4;
    #pragma unroll
    for (int r = 0; r < 4; ++r) {
      const int gi = gibase + r;
      const float di = dvec[gi];  // fp32 diagonal (accurate)
      #pragma unroll
      for (int ni = 0; ni < 4; ++ni) {
        const int gj = bx * BN + wn * 64 + ni * 16 + lrow;
        const float s = acc[mi][ni][r];
        lsum += (gi == gj) ? (1.0f - s) : fmaxf(MARGIN - s + di, 0.0f);
      }
    }
  }
  #pragma unroll
  for (int off = 32; off; off >>= 1) lsum += __shfl_down(lsum, off, 64);
  __shared__ float bsum[4];
  if (ln == 0) bsum[wv] = lsum;
  __syncthreads();
  if (t == 0) {
    const float tot = (bsum[0] + bsum[1] + bsum[2] + bsum[3]) *
                      (1.0f / ((float)N * (float)N));
    atomicAdd(out, tot);
  }
}

extern "C" void kernel_launch(void* const* d_in, const int* in_sizes, int n_in,
                              void* d_out, int out_size, void* d_ws, size_t ws_size,
                              hipStream_t stream) {
  const float* W = (const float*)d_in[0];  // wsi_embeddings (N,1,D)
  const float* O = (const float*)d_in[1];  // omic_embeddings (N,1,D)
  uint8_t* Wn = (uint8_t*)d_ws;                     // 4 MB fp8
  uint8_t* On = Wn + (size_t)N * D;                 // 4 MB fp8
  float* dvec = (float*)(On + (size_t)N * D);       // 16 KB
  float* out = (float*)d_out;

  prep_kernel<<<N / 4, 256, 0, stream>>>(W, O, Wn, On, dvec, out);
  dim3 grid(N / BN, N / BM);  // 32 x 16 = 512 blocks
  gemm_loss_kernel<<<grid, 256, 0, stream>>>(Wn, On, dvec, out);
}